// Round 6
// baseline (274.533 us; speedup 1.0000x reference)
//
#include <hip/hip_runtime.h>
#include <math.h>

#define BN 16
#define BC 256
#define BM 63
#define MO 56
#define PLANE (BM * BM)          // 3969
#define SHALF 72                 // x slice row stride in halves (144 B)
#define XSLICE_B (BM * SHALF * 2)  // 9072 B
#define SLICE_B 9216             // x slice + z (128 B) + pad, 16B aligned
#define WPB 4                    // waves per block, one channel each
#define NT 256
#define NCHUNK (BC / WPB)        // 64 -> grid 16x64 = 1024 blocks, 16 waves/CU
#define OUTPLANE (MO * MO)       // 3136

typedef _Float16 half_t;
typedef __attribute__((ext_vector_type(8))) _Float16 half8;

template <bool USE_WS>
__global__ __launch_bounds__(NT, 4)
void bhat_partial(const float* __restrict__ z, const float* __restrict__ x,
                  const float* __restrict__ w, float* __restrict__ dst)
{
    __shared__ __align__(16) char smem[WPB * SLICE_B];   // 36864 B

    const int n    = blockIdx.x;
    const int wv   = threadIdx.x >> 6;
    const int lane = threadIdx.x & 63;
    const int c    = blockIdx.y * WPB + wv;      // this wave's channel
    const int ly   = lane >> 3;                  // 0..7
    const int lxr  = lane & 7;
    const int lx   = (lxr < 7) ? lxr : 6;        // dup lane -> broadcast reads
    const int row0 = ly * 7;                     // 0..49
    const int col0 = lx * 8;                     // 0..48 (x16B aligned in LDS)

    half_t* xsh = (half_t*)(smem + wv * SLICE_B);
    half_t* zsh = (half_t*)(smem + wv * SLICE_B + XSLICE_B);

    // ---- stage sqrt(x[n,c]) as f16 into this wave's private slice ----
    const float* __restrict__ xp = x + (size_t)(n * BC + c) * PLANE;
    for (int j = 0; j < 62; ++j) {               // 62*64 = 3968
        int i  = lane + 64 * j;
        int r  = (int)((unsigned)i / 63u);
        int cc = i - r * 63;
        xsh[r * SHALF + cc] = (half_t)sqrtf(xp[i]);
    }
    if (lane == 0) xsh[62 * SHALF + 62] = (half_t)sqrtf(xp[3968]);

    // ---- stage w*sqrt(z)/64 as 64 f16 ----
    const float wsc = w[c] * (1.0f / 64.0f);
    zsh[lane] = (half_t)(sqrtf(z[(size_t)(n * BC + c) * 64 + lane]) * wsc);

    __syncthreads();   // LDS staging visible (also cross-lane within wave)

    // z rows as 8 half8 = 8 VGPRs, uniform-address broadcast reads
    half8 zr[8];
#pragma unroll
    for (int p = 0; p < 8; ++p) zr[p] = ((const half8*)zsh)[p];

    float acc[7][8];
#pragma unroll
    for (int a = 0; a < 7; ++a)
#pragma unroll
        for (int b = 0; b < 8; ++b) acc[a][b] = 0.0f;

    // ---- each of the 14 window rows read exactly once ----
#pragma unroll
    for (int r = 0; r < 14; ++r) {
        const half8* xrp = (const half8*)(xsh + (row0 + r) * SHALF + col0);
        half8 x0 = xrp[0];   // halves [col0, col0+8)
        half8 x1 = xrp[1];   // halves [col0+8, col0+16)
#pragma unroll
        for (int a = 0; a < 7; ++a) {
            const int p = r - a;
            if (p < 0 || p > 7) continue;        // compile-time pruned
#pragma unroll
            for (int q = 0; q < 8; ++q) {
                const float zv = (float)zr[p][q];
#pragma unroll
                for (int b = 0; b < 8; ++b) {
                    const int idx = q + b;       // 0..14
                    const float xv = (float)(idx < 8 ? x0[idx] : x1[idx - 8]);
                    acc[a][b] = fmaf(xv, zv, acc[a][b]);
                }
            }
        }
    }

    // ---- cross-wave (4-channel) reduction in LDS ----
    __syncthreads();                       // everyone done reading slices
    float* red = (float*)smem;             // 3136 f32 = 12544 B, fits in smem
    for (int i = threadIdx.x; i < OUTPLANE; i += NT) red[i] = 0.0f;
    __syncthreads();
    if (lxr < 7) {
#pragma unroll
        for (int a = 0; a < 7; ++a)
#pragma unroll
            for (int b = 0; b < 8; ++b)
                unsafeAtomicAdd(&red[(row0 + a) * MO + col0 + b], acc[a][b]);  // ds_add_f32
    }
    __syncthreads();

    if (USE_WS) {
        // plain coalesced stores of this block's partial plane
        float* __restrict__ pp = dst + ((size_t)n * NCHUNK + blockIdx.y) * OUTPLANE;
        for (int i = threadIdx.x; i < OUTPLANE; i += NT) pp[i] = red[i];
    } else {
        float* __restrict__ op = dst + (size_t)n * OUTPLANE;
        for (int i = threadIdx.x; i < OUTPLANE; i += NT) unsafeAtomicAdd(op + i, red[i]);
    }
}

__global__ __launch_bounds__(256)
void reduce_k(const float* __restrict__ part, float* __restrict__ out)
{
    int i = blockIdx.x * 256 + threadIdx.x;      // 0..50175 (196*256 exact)
    int n = i / OUTPLANE;
    int j = i - n * OUTPLANE;
    const float* __restrict__ p = part + (size_t)n * NCHUNK * OUTPLANE + j;
    float s = 0.0f;
#pragma unroll 16
    for (int k = 0; k < NCHUNK; ++k) s += p[(size_t)k * OUTPLANE];
    out[i] = s;
}

extern "C" void kernel_launch(void* const* d_in, const int* in_sizes, int n_in,
                              void* d_out, int out_size, void* d_ws, size_t ws_size,
                              hipStream_t stream) {
    const float* z = (const float*)d_in[0];   // (16,256,8,8)
    const float* x = (const float*)d_in[1];   // (16,256,63,63)
    const float* w = (const float*)d_in[2];   // (256)
    float* out = (float*)d_out;               // (16,1,56,56)

    const size_t need = (size_t)BN * NCHUNK * OUTPLANE * sizeof(float);  // 12.85 MB
    dim3 grid(BN, NCHUNK);
    if (ws_size >= need) {
        float* part = (float*)d_ws;
        bhat_partial<true><<<grid, NT, 0, stream>>>(z, x, w, part);
        reduce_k<<<BN * OUTPLANE / 256, 256, 0, stream>>>(part, out);
    } else {
        (void)hipMemsetAsync(out, 0, (size_t)out_size * sizeof(float), stream);
        bhat_partial<false><<<grid, NT, 0, stream>>>(z, x, w, out);
    }
}